// Round 13
// baseline (547.273 us; speedup 1.0000x reference)
//
#include <hip/hip_runtime.h>

#define BQ 256
#define TQ 1024
#define FQ 37
#define UQ 64
#define G3 192
#define CH 8
#define NCK (TQ / CH)
#define CFD (CH * FQ)   // 296 dwords per staged chunk

__device__ __forceinline__ float sigmoid_f(float x) {
    return 1.0f / (1.0f + __expf(-x));
}
__device__ __forceinline__ float tanh_f(float x) {
    return 1.0f - 2.0f / (__expf(2.0f * x) + 1.0f);
}

#define PIN8(A, U) asm volatile("" : "+v"(A[U]), "+v"(A[U+1]), "+v"(A[U+2]), \
    "+v"(A[U+3]), "+v"(A[U+4]), "+v"(A[U+5]), "+v"(A[U+6]), "+v"(A[U+7]))

// 3 waves / block (R12 + final-chunk race fix):
//  R11/R12 failed with BIT-IDENTICAL absmax (1.171875e-2) across different
//  summation groupings -> not numerics: the mid-step barrier left step 1023's
//  s_h8 write uncovered, so the producer's epilogue HEAD raced and read the
//  stale h (t=1007) for out[:,1023] (wrong only for len>1007 batches).
//  FIX: one trailing lgkmcnt+barrier for ALL waves before the final HEAD.
//  waves 0,1 = consumers split by u-half (96 pinned weight regs each);
//  per step: 32 readlane + 96 fma; partials exchanged via one b128 pair
//  around the per-step barrier; gates redundant, FIXED A+B order.
//  wave 2 = producer: stage 2 ahead, packed xp 1 ahead, head 1 behind.
__global__ __launch_bounds__(192)
__attribute__((amdgpu_waves_per_eu(1, 1)))
void gru_split(const float* __restrict__ values,   // [B,T,F]
               const int*   __restrict__ lengths,  // [B]
               const float* __restrict__ Wk,       // [F,3U]
               const float* __restrict__ Wr,       // [U,3U]
               const float* __restrict__ bias,     // [2,3U]
               const float* __restrict__ dw,       // [U]
               const float* __restrict__ db,       // [1]
               float*       __restrict__ out)      // [B,T]
{
    const int tid = threadIdx.x;
    const int j   = tid & 63;
    const int w   = tid >> 6;
    const int b   = blockIdx.x;

    __shared__ __align__(16) float s_v[2][CH][40];        // staged values
    __shared__ __align__(16) float s_xp[2][CH][64][4];    // packed xp {z,r,h,_}
    __shared__ __align__(16) float s_part[2][2][64][4];   // partials {az,ar,ah,_}
    __shared__ __align__(16) float s_h8[2][CH][76];       // h history

    const float* vbp = values + (size_t)b * TQ * FQ;
    float* ob = out + (size_t)b * TQ;

    if (w < 2) {
        // ================= CONSUMERS =================
        float Rz[32], Rr[32], Rh[32];
#pragma unroll
        for (int i = 0; i < 32; ++i) {
            const int u = w * 32 + i;
            Rz[i] = Wr[u * G3 + j];
            Rr[i] = Wr[u * G3 + 64 + j];
            Rh[i] = Wr[u * G3 + 128 + j];
        }
#pragma unroll
        for (int i = 0; i < 32; i += 8) { PIN8(Rz, i); PIN8(Rr, i); PIN8(Rh, i); }
        const float bh_r = (w == 0) ? bias[G3 + 128 + j] : 0.0f; // into A-half
        const int len = lengths[b];

        __builtin_amdgcn_s_barrier();            // prologue barrier

        float h = 0.0f;                          // lane j holds h_j (both waves)
#pragma unroll 1
        for (int k = 0; k < NCK; ++k) {
            const int pb = k & 1;
#pragma unroll 1
            for (int tc = 0; tc < CH; ++tc) {
                const int t   = k * CH + tc;
                const int buf = t & 1;
                const float4 xpv = *(const float4*)&s_xp[pb][tc][j][0];

                const int hbits = __float_as_int(h);
                float az0 = 0.f, az1 = 0.f, ar0 = 0.f, ar1 = 0.f,
                      ah0 = 0.f, ah1 = 0.f;
                if (w == 0) {
#pragma unroll
                    for (int i = 0; i < 32; i += 2) {
                        const float h0 = __int_as_float(
                            __builtin_amdgcn_readlane(hbits, i));
                        const float h1 = __int_as_float(
                            __builtin_amdgcn_readlane(hbits, i + 1));
                        az0 += h0 * Rz[i];   az1 += h1 * Rz[i + 1];
                        ar0 += h0 * Rr[i];   ar1 += h1 * Rr[i + 1];
                        ah0 += h0 * Rh[i];   ah1 += h1 * Rh[i + 1];
                    }
                } else {
#pragma unroll
                    for (int i = 0; i < 32; i += 2) {
                        const float h0 = __int_as_float(
                            __builtin_amdgcn_readlane(hbits, 32 + i));
                        const float h1 = __int_as_float(
                            __builtin_amdgcn_readlane(hbits, 32 + i + 1));
                        az0 += h0 * Rz[i];   az1 += h1 * Rz[i + 1];
                        ar0 += h0 * Rr[i];   ar1 += h1 * Rr[i + 1];
                        ah0 += h0 * Rh[i];   ah1 += h1 * Rh[i + 1];
                    }
                }
                const float az = az0 + az1;
                const float ar = ar0 + ar1;
                const float ah = (ah0 + ah1) + bh_r;
                float4 mine; mine.x = az; mine.y = ar; mine.z = ah; mine.w = 0.f;
                *(float4*)&s_part[buf][w][j][0] = mine;
                asm volatile("s_waitcnt lgkmcnt(0)" ::: "memory");
                __builtin_amdgcn_sched_barrier(0);
                __builtin_amdgcn_s_barrier();
                __builtin_amdgcn_sched_barrier(0);
                const float4 o = *(const float4*)&s_part[buf][w ^ 1][j][0];

                // ---- FIXED ORDER: A = u0..31 partial, B = u32..63 partial ----
                float Az, Bz, Ar, Br, Ah, Bh;
                if (w == 0) { Az = az;  Bz = o.x; Ar = ar;  Br = o.y; Ah = ah;  Bh = o.z; }
                else        { Az = o.x; Bz = az;  Ar = o.y; Br = ar;  Ah = o.z; Bh = ah; }

                const float z  = sigmoid_f(xpv.x + (Az + Bz));
                const float r  = sigmoid_f(xpv.y + (Ar + Br));
                const float cc = tanh_f(xpv.z + r * (Ah + Bh));
                const float hn = z * h + (1.0f - z) * cc;
                h = (t < len) ? hn : h;          // Keras masking
                if (w == 0) s_h8[pb][tc][j] = h; // for the head
            }
        }
        // ---- trailing barrier: covers step 1023's s_h8 write (the R11/12 race)
        asm volatile("s_waitcnt lgkmcnt(0)" ::: "memory");
        __builtin_amdgcn_s_barrier();
    } else {
        // ================= PRODUCER =================
        float Kz[FQ], Kr[FQ], Kh[FQ];
#pragma unroll
        for (int f = 0; f < FQ; ++f) {
            Kz[f] = Wk[f * G3 + j];
            Kr[f] = Wk[f * G3 + 64 + j];
            Kh[f] = Wk[f * G3 + 128 + j];
        }
        const float bz  = bias[j] + bias[G3 + j];            // fold rec bias z
        const float br  = bias[64 + j] + bias[G3 + 64 + j];  // fold rec bias r
        const float bhx = bias[128 + j];                     // input bias only
        const float dbv = db[0];
        float dwv[8];
#pragma unroll
        for (int i = 0; i < 8; ++i) dwv[i] = dw[(j & 7) * 8 + i];

        int rq[5], cq[5];
        bool act[5];
        float stg[5];
#pragma unroll
        for (int q = 0; q < 5; ++q) {
            const int idx = j + 64 * q;
            act[q] = idx < CFD;
            rq[q] = idx / FQ;
            cq[q] = idx - rq[q] * FQ;
            stg[q] = 0.0f;
        }

#define STAGE_LOAD(CK)                                                        \
        _Pragma("unroll")                                                     \
        for (int q = 0; q < 5; ++q)                                           \
            if (act[q]) stg[q] = vbp[(size_t)(CK) * CFD + j + 64 * q];
#define STAGE_WRITE(SB)                                                       \
        _Pragma("unroll")                                                     \
        for (int q = 0; q < 5; ++q)                                           \
            if (act[q]) s_v[SB][rq[q]][cq[q]] = stg[q];

#define XF(VAL, I) { az += (VAL) * Kz[I]; ar += (VAL) * Kr[I]; ah += (VAL) * Kh[I]; }
#define XPROW(BB, ROW)                                                        \
    {                                                                         \
        const float4* vr = (const float4*)&s_v[BB][ROW][0];                   \
        float az = bz, ar = br, ah = bhx;                                     \
        { float4 v0 = vr[0], v1 = vr[1], v2 = vr[2];                          \
          XF(v0.x, 0)  XF(v0.y, 1)  XF(v0.z, 2)  XF(v0.w, 3)                  \
          XF(v1.x, 4)  XF(v1.y, 5)  XF(v1.z, 6)  XF(v1.w, 7)                  \
          XF(v2.x, 8)  XF(v2.y, 9)  XF(v2.z, 10) XF(v2.w, 11) }               \
        { float4 v3 = vr[3], v4 = vr[4], v5 = vr[5];                          \
          XF(v3.x, 12) XF(v3.y, 13) XF(v3.z, 14) XF(v3.w, 15)                 \
          XF(v4.x, 16) XF(v4.y, 17) XF(v4.z, 18) XF(v4.w, 19)                 \
          XF(v5.x, 20) XF(v5.y, 21) XF(v5.z, 22) XF(v5.w, 23) }               \
        { float4 v6 = vr[6], v7 = vr[7], v8 = vr[8];                          \
          float f36 = s_v[BB][ROW][36];                                       \
          XF(v6.x, 24) XF(v6.y, 25) XF(v6.z, 26) XF(v6.w, 27)                 \
          XF(v7.x, 28) XF(v7.y, 29) XF(v7.z, 30) XF(v7.w, 31)                 \
          XF(v8.x, 32) XF(v8.y, 33) XF(v8.z, 34) XF(v8.w, 35)                 \
          XF(f36, 36) }                                                       \
        float4 xo; xo.x = az; xo.y = ar; xo.z = ah; xo.w = 0.f;               \
        *(float4*)&s_xp[BB][ROW][j][0] = xo;                                  \
    }

#define HEAD(HB, TB)                                                          \
    {                                                                         \
        const int e = j & 7, s = j >> 3;                                      \
        const float4* hr = (const float4*)&s_h8[HB][s][e * 8];                \
        float4 ha = hr[0], hc = hr[1];                                        \
        float pp = ha.x * dwv[0] + ha.y * dwv[1] + ha.z * dwv[2]              \
                 + ha.w * dwv[3] + hc.x * dwv[4] + hc.y * dwv[5]              \
                 + hc.z * dwv[6] + hc.w * dwv[7];                             \
        pp += __shfl_xor(pp, 1, 64);                                          \
        pp += __shfl_xor(pp, 2, 64);                                          \
        pp += __shfl_xor(pp, 4, 64);                                          \
        if (e == 0) ob[(TB) + s] = sigmoid_f(pp + dbv);                       \
    }

        // prologue: chunk0 -> s_v[0]; chunk1 -> s_v[1]; issue chunk2; xp(chunk0)
        STAGE_LOAD(0)
        asm volatile("s_waitcnt vmcnt(0)" ::: "memory");
        STAGE_WRITE(0)
        STAGE_LOAD(1)
        asm volatile("s_waitcnt vmcnt(0)" ::: "memory");
        STAGE_WRITE(1)
        STAGE_LOAD(2)
        asm volatile("s_waitcnt lgkmcnt(0)" ::: "memory");  // own s_v visible
#pragma unroll 1
        for (int s = 0; s < CH; ++s) XPROW(0, s)
        asm volatile("s_waitcnt lgkmcnt(0)" ::: "memory");
        __builtin_amdgcn_s_barrier();            // prologue barrier

#pragma unroll 1
        for (int k = 0; k < NCK; ++k) {
            const int pb = k & 1, nb = pb ^ 1;
#pragma unroll 1
            for (int tc = 0; tc < CH; ++tc) {
                if (tc == 0 && (k + 2) < NCK) {
                    asm volatile("s_waitcnt vmcnt(0)" ::: "memory");
                    STAGE_WRITE(pb)              // chunk k+2
                }
                if (tc == 1) {
                    if ((k + 3) < NCK) STAGE_LOAD(k + 3)
                    if (k > 0) HEAD(nb, (k - 1) * CH)
                }
                if ((k + 1) < NCK) XPROW(nb, tc) // row tc of chunk k+1
                asm volatile("s_waitcnt lgkmcnt(0)" ::: "memory");
                __builtin_amdgcn_s_barrier();    // per-step barrier
            }
        }
        // ---- trailing barrier (matches consumers), then the final head ----
        asm volatile("s_waitcnt lgkmcnt(0)" ::: "memory");
        __builtin_amdgcn_s_barrier();
        HEAD((NCK - 1) & 1, (NCK - 1) * CH)

#undef STAGE_LOAD
#undef STAGE_WRITE
#undef XF
#undef XPROW
#undef HEAD
    }
}

extern "C" void kernel_launch(void* const* d_in, const int* in_sizes, int n_in,
                              void* d_out, int out_size, void* d_ws, size_t ws_size,
                              hipStream_t stream) {
    const float* values  = (const float*)d_in[2];
    const int*   lengths = (const int*)  d_in[4];
    const float* Wk      = (const float*)d_in[5];
    const float* Wr      = (const float*)d_in[6];
    const float* bias    = (const float*)d_in[7];
    const float* dw      = (const float*)d_in[8];
    const float* db      = (const float*)d_in[9];
    float* out = (float*)d_out;

    gru_split<<<dim3(BQ), dim3(192), 0, stream>>>(
        values, lengths, Wk, Wr, bias, dw, db, out);
}

// Round 14
// 540.558 us; speedup vs baseline: 1.0124x; 1.0124x over previous
//
#include <hip/hip_runtime.h>

#define BQ 256
#define TQ 1024
#define FQ 37
#define UQ 64
#define G3 192
#define CH 8
#define NCK (TQ / CH)
#define CFD (CH * FQ)   // 296 dwords per staged chunk

typedef float v2f __attribute__((ext_vector_type(2)));

__device__ __forceinline__ float sigmoid_f(float x) {
    return 1.0f / (1.0f + __expf(-x));
}
__device__ __forceinline__ float tanh_f(float x) {
    return 1.0f - 2.0f / (__expf(2.0f * x) + 1.0f);
}

#define PINP4(A, I) asm volatile("" : "+v"(A[I]), "+v"(A[I+1]), \
    "+v"(A[I+2]), "+v"(A[I+3]))

// R10 structure (best: 524us) with the consumer GEMV re-issued as packed math:
//  wave0 consumer: weights as 96 float2 pairs -> 96 v_pk_fma_f32 per step
//        (was 192 scalar fma). h broadcast: 64 readlane -> 32 SGPR pairs via
//        SALU pack (parallel pipe). Readlanes batched 16-ahead (no SGPR-write
//        hazard stalls). asm "v" operands force arch-VGPR residency (AGPRs
//        can't feed asm) — fixes R10's VGPR=148 placement. ~225 live < 256.
//  wave1 producer: unchanged from R10 (stage 2 ahead, xp 1 ahead, head 1
//        behind; chunk-level barriers only; final HEAD after last barrier).
__global__ __launch_bounds__(128)
__attribute__((amdgpu_waves_per_eu(1, 1)))
void gru_pk(const float* __restrict__ values,   // [B,T,F]
            const int*   __restrict__ lengths,  // [B]
            const float* __restrict__ Wk,       // [F,3U]
            const float* __restrict__ Wr,       // [U,3U]
            const float* __restrict__ bias,     // [2,3U]
            const float* __restrict__ dw,       // [U]
            const float* __restrict__ db,       // [1]
            float*       __restrict__ out)      // [B,T]
{
    const int tid = threadIdx.x;
    const int j   = tid & 63;
    const int w   = tid >> 6;
    const int b   = blockIdx.x;

    __shared__ __align__(16) float s_v[2][CH][40];   // staged values (dbuf)
    __shared__ float s_xp[2][CH][G3];                // x-projections (dbuf)
    __shared__ __align__(16) float s_h8[2][CH][76];  // h history (padded rows)

    const float* vbp = values + (size_t)b * TQ * FQ;
    float* ob = out + (size_t)b * TQ;

    if (w == 0) {
        // ================= CONSUMER =================
        v2f Pz[32], Pr[32], Ph[32];      // weight pairs over u: {W[2i], W[2i+1]}
#pragma unroll
        for (int i = 0; i < 32; ++i) {
            v2f tz, tr, th;
            tz.x = Wr[(2 * i) * G3 + j];        tz.y = Wr[(2 * i + 1) * G3 + j];
            tr.x = Wr[(2 * i) * G3 + 64 + j];   tr.y = Wr[(2 * i + 1) * G3 + 64 + j];
            th.x = Wr[(2 * i) * G3 + 128 + j];  th.y = Wr[(2 * i + 1) * G3 + 128 + j];
            Pz[i] = tz; Pr[i] = tr; Ph[i] = th;
        }
#pragma unroll
        for (int i = 0; i < 32; i += 4) { PINP4(Pz, i); PINP4(Pr, i); PINP4(Ph, i); }

        const float bh = bias[G3 + 128 + j];     // h-gate recurrent bias
        const int len = lengths[b];

        __builtin_amdgcn_s_barrier();            // prologue barrier

        float h = 0.0f;                          // lane j holds h_j
#pragma unroll 1
        for (int k = 0; k < NCK; ++k) {
            const int pb = k & 1;
            const int tbase = k * CH;
            float cz = s_xp[pb][0][j];
            float cr = s_xp[pb][0][64 + j];
            float cx = s_xp[pb][0][128 + j];
#pragma unroll 1
            for (int tc = 0; tc < CH; ++tc) {
                const int tn = (tc + 1) & (CH - 1);  // tc=7 -> row0 (discarded)
                const float nz = s_xp[pb][tn][j];
                const float nr = s_xp[pb][tn][64 + j];
                const float nx = s_xp[pb][tn][128 + j];

                const int hbits = __float_as_int(h);
                v2f azp; azp.x = 0.f; azp.y = 0.f;
                v2f arp; arp.x = 0.f; arp.y = 0.f;
                v2f ahp; ahp.x = 0.f; ahp.y = 0.f;
#pragma unroll
                for (int g = 0; g < 4; ++g) {    // groups: 16 readlane, 8 pack, 24 pk_fma
                    unsigned long long hp0, hp1, hp2, hp3, hp4, hp5, hp6, hp7;
#define MKPAIR(Q)                                                             \
    {                                                                         \
        const unsigned int h0 = (unsigned int)__builtin_amdgcn_readlane(      \
            hbits, g * 16 + (Q) * 2);                                         \
        const unsigned int h1 = (unsigned int)__builtin_amdgcn_readlane(      \
            hbits, g * 16 + (Q) * 2 + 1);                                     \
        hp##Q = ((unsigned long long)h1 << 32) | (unsigned long long)h0;      \
    }
                    MKPAIR(0) MKPAIR(1) MKPAIR(2) MKPAIR(3)
                    MKPAIR(4) MKPAIR(5) MKPAIR(6) MKPAIR(7)
#undef MKPAIR
#define PKFMA(Q)                                                              \
    asm("v_pk_fma_f32 %0, %1, %2, %0" : "+v"(azp) : "v"(Pz[g * 8 + (Q)]), "s"(hp##Q)); \
    asm("v_pk_fma_f32 %0, %1, %2, %0" : "+v"(arp) : "v"(Pr[g * 8 + (Q)]), "s"(hp##Q)); \
    asm("v_pk_fma_f32 %0, %1, %2, %0" : "+v"(ahp) : "v"(Ph[g * 8 + (Q)]), "s"(hp##Q));
                    PKFMA(0) PKFMA(1) PKFMA(2) PKFMA(3)
                    PKFMA(4) PKFMA(5) PKFMA(6) PKFMA(7)
#undef PKFMA
                }
                // horizontal adds: same grouping as R10's (even+odd) -> bit-identical
                const float az = azp.x + azp.y;
                const float ar = arp.x + arp.y;
                const float ah = ahp.x + ahp.y;

                const float z  = sigmoid_f(cz + az);
                const float r  = sigmoid_f(cr + ar);
                const float cc = tanh_f(cx + r * (bh + ah));
                const float hn = z * h + (1.0f - z) * cc;
                h = ((tbase + tc) < len) ? hn : h;
                s_h8[pb][tc][j] = h;

                cz = nz; cr = nr; cx = nx;
            }
            asm volatile("s_waitcnt lgkmcnt(0)" ::: "memory");
            __builtin_amdgcn_s_barrier();        // once per 8 steps
        }
    } else {
        // ================= PRODUCER (verbatim R10) =================
        float Kz[FQ], Kr[FQ], Kh[FQ];
#pragma unroll
        for (int f = 0; f < FQ; ++f) {
            Kz[f] = Wk[f * G3 + j];
            Kr[f] = Wk[f * G3 + 64 + j];
            Kh[f] = Wk[f * G3 + 128 + j];
        }
        const float bz  = bias[j] + bias[G3 + j];            // fold rec bias z
        const float br  = bias[64 + j] + bias[G3 + 64 + j];  // fold rec bias r
        const float bhx = bias[128 + j];                     // input bias only
        const float dbv = db[0];
        float dwv[8];
#pragma unroll
        for (int i = 0; i < 8; ++i) dwv[i] = dw[(j & 7) * 8 + i];

        int rq[5], cq[5];
        bool act[5];
        float stg[5];
#pragma unroll
        for (int q = 0; q < 5; ++q) {
            const int idx = j + 64 * q;
            act[q] = idx < CFD;
            rq[q] = idx / FQ;
            cq[q] = idx - rq[q] * FQ;
            stg[q] = 0.0f;
        }

#define STAGE_LOAD(CK)                                                        \
        _Pragma("unroll")                                                     \
        for (int q = 0; q < 5; ++q)                                           \
            if (act[q]) stg[q] = vbp[(size_t)(CK) * CFD + j + 64 * q];
#define STAGE_WRITE(SB)                                                       \
        _Pragma("unroll")                                                     \
        for (int q = 0; q < 5; ++q)                                           \
            if (act[q]) s_v[SB][rq[q]][cq[q]] = stg[q];

#define XF(VAL, I) { az += (VAL) * Kz[I]; ar += (VAL) * Kr[I]; ah += (VAL) * Kh[I]; }
#define XPROW(BB)                                                             \
    _Pragma("unroll 1")                                                       \
    for (int row = 0; row < CH; ++row) {                                      \
        const float4* vr = (const float4*)&s_v[BB][row][0];                   \
        float az = bz, ar = br, ah = bhx;                                     \
        { float4 v0 = vr[0], v1 = vr[1], v2 = vr[2];                          \
          XF(v0.x, 0)  XF(v0.y, 1)  XF(v0.z, 2)  XF(v0.w, 3)                  \
          XF(v1.x, 4)  XF(v1.y, 5)  XF(v1.z, 6)  XF(v1.w, 7)                  \
          XF(v2.x, 8)  XF(v2.y, 9)  XF(v2.z, 10) XF(v2.w, 11) }               \
        { float4 v3 = vr[3], v4 = vr[4], v5 = vr[5];                          \
          XF(v3.x, 12) XF(v3.y, 13) XF(v3.z, 14) XF(v3.w, 15)                 \
          XF(v4.x, 16) XF(v4.y, 17) XF(v4.z, 18) XF(v4.w, 19)                 \
          XF(v5.x, 20) XF(v5.y, 21) XF(v5.z, 22) XF(v5.w, 23) }               \
        { float4 v6 = vr[6], v7 = vr[7], v8 = vr[8];                          \
          float f36 = s_v[BB][row][36];                                       \
          XF(v6.x, 24) XF(v6.y, 25) XF(v6.z, 26) XF(v6.w, 27)                 \
          XF(v7.x, 28) XF(v7.y, 29) XF(v7.z, 30) XF(v7.w, 31)                 \
          XF(v8.x, 32) XF(v8.y, 33) XF(v8.z, 34) XF(v8.w, 35)                 \
          XF(f36, 36) }                                                       \
        s_xp[BB][row][j]       = az;                                          \
        s_xp[BB][row][64 + j]  = ar;                                          \
        s_xp[BB][row][128 + j] = ah;                                          \
    }

#define HEAD(HB, TB)                                                          \
    {                                                                         \
        const int e = j & 7, s = j >> 3;                                      \
        const float4* hr = (const float4*)&s_h8[HB][s][e * 8];                \
        float4 ha = hr[0], hc = hr[1];                                        \
        float pp = ha.x * dwv[0] + ha.y * dwv[1] + ha.z * dwv[2]              \
                 + ha.w * dwv[3] + hc.x * dwv[4] + hc.y * dwv[5]              \
                 + hc.z * dwv[6] + hc.w * dwv[7];                             \
        pp += __shfl_xor(pp, 1, 64);                                          \
        pp += __shfl_xor(pp, 2, 64);                                          \
        pp += __shfl_xor(pp, 4, 64);                                          \
        if (e == 0) ob[(TB) + s] = sigmoid_f(pp + dbv);                       \
    }

        // prologue: chunk0 -> s_v[0]; chunk1 -> s_v[1]; issue chunk2; xp(chunk0)
        STAGE_LOAD(0)
        asm volatile("s_waitcnt vmcnt(0)" ::: "memory");
        STAGE_WRITE(0)
        STAGE_LOAD(1)
        asm volatile("s_waitcnt vmcnt(0)" ::: "memory");
        STAGE_WRITE(1)
        STAGE_LOAD(2)
        asm volatile("s_waitcnt lgkmcnt(0)" ::: "memory");  // own s_v visible
        XPROW(0)
        asm volatile("s_waitcnt lgkmcnt(0)" ::: "memory");
        __builtin_amdgcn_s_barrier();            // prologue barrier

#pragma unroll 1
        for (int k = 0; k < NCK; ++k) {
            const int pb = k & 1, nb = pb ^ 1;
            if (k > 0) HEAD(nb, (k - 1) * CH)
            if (k + 2 < NCK) {
                asm volatile("s_waitcnt vmcnt(0)" ::: "memory");
                STAGE_WRITE(pb)                  // chunk k+2
                if (k + 3 < NCK) STAGE_LOAD(k + 3)
            }
            if (k + 1 < NCK) XPROW(nb)           // xp chunk k+1 from s_v[nb]
            asm volatile("s_waitcnt lgkmcnt(0)" ::: "memory");
            __builtin_amdgcn_s_barrier();        // once per 8 steps
        }
        HEAD((NCK - 1) & 1, (NCK - 1) * CH)      // after final barrier: race-free

#undef STAGE_LOAD
#undef STAGE_WRITE
#undef XF
#undef XPROW
#undef HEAD
    }
}

extern "C" void kernel_launch(void* const* d_in, const int* in_sizes, int n_in,
                              void* d_out, int out_size, void* d_ws, size_t ws_size,
                              hipStream_t stream) {
    const float* values  = (const float*)d_in[2];
    const int*   lengths = (const int*)  d_in[4];
    const float* Wk      = (const float*)d_in[5];
    const float* Wr      = (const float*)d_in[6];
    const float* bias    = (const float*)d_in[7];
    const float* dw      = (const float*)d_in[8];
    const float* db      = (const float*)d_in[9];
    float* out = (float*)d_out;

    gru_pk<<<dim3(BQ), dim3(128), 0, stream>>>(
        values, lengths, Wk, Wr, bias, dw, db, out);
}

// Round 15
// 486.449 us; speedup vs baseline: 1.1250x; 1.1112x over previous
//
#include <hip/hip_runtime.h>

#define BQ 256
#define TQ 1024
#define FQ 37
#define UQ 64
#define G3 192
#define CH 8
#define NCK (TQ / CH)
#define CFD (CH * FQ)   // 296 dwords per staged chunk

typedef float v2f __attribute__((ext_vector_type(2)));

__device__ __forceinline__ float sigmoid_f(float x) {
    return 1.0f / (1.0f + __expf(-x));
}
__device__ __forceinline__ float tanh_f(float x) {
    return 1.0f - 2.0f / (__expf(2.0f * x) + 1.0f);
}

#define PINP4(A, I) asm volatile("" : "+v"(A[I]), "+v"(A[I+1]), \
    "+v"(A[I+2]), "+v"(A[I+3]))

// R14 structure with the h-broadcast switched from 64 v_readlane (SGPR-write
// hazard ~15cy each with 1 wave/EU = the ~1000cy/step mystery term; R10/R13/
// R14 all consistent) to LDS UNIFORM READS (same-address b128 = free HW
// broadcast): consumer writes h_j to s_h8 each step (already needed for the
// head), then reads the whole h vector back as 16 uniform ds_read_b128 in two
// reg-reused halves. Same-wave write->read ordered by lgkmcnt(0); NO new
// barriers (chunk cadence kept). pk_fma chain + summation order bit-identical
// to R14 (absmax 0.0).
__global__ __launch_bounds__(128)
__attribute__((amdgpu_waves_per_eu(1, 1)))
void gru_ldsb(const float* __restrict__ values,   // [B,T,F]
              const int*   __restrict__ lengths,  // [B]
              const float* __restrict__ Wk,       // [F,3U]
              const float* __restrict__ Wr,       // [U,3U]
              const float* __restrict__ bias,     // [2,3U]
              const float* __restrict__ dw,       // [U]
              const float* __restrict__ db,       // [1]
              float*       __restrict__ out)      // [B,T]
{
    const int tid = threadIdx.x;
    const int j   = tid & 63;
    const int w   = tid >> 6;
    const int b   = blockIdx.x;

    __shared__ __align__(16) float s_v[2][CH][40];   // staged values (dbuf)
    __shared__ float s_xp[2][CH][G3];                // x-projections (dbuf)
    __shared__ __align__(16) float s_h8[2][CH][76];  // h history (76*4=304, 16B-mult)

    const float* vbp = values + (size_t)b * TQ * FQ;
    float* ob = out + (size_t)b * TQ;

    if (w == 0) {
        // ================= CONSUMER =================
        v2f Pz[32], Pr[32], Ph[32];      // weight pairs over u: {W[2i], W[2i+1]}
#pragma unroll
        for (int i = 0; i < 32; ++i) {
            v2f tz, tr, th;
            tz.x = Wr[(2 * i) * G3 + j];        tz.y = Wr[(2 * i + 1) * G3 + j];
            tr.x = Wr[(2 * i) * G3 + 64 + j];   tr.y = Wr[(2 * i + 1) * G3 + 64 + j];
            th.x = Wr[(2 * i) * G3 + 128 + j];  th.y = Wr[(2 * i + 1) * G3 + 128 + j];
            Pz[i] = tz; Pr[i] = tr; Ph[i] = th;
        }
#pragma unroll
        for (int i = 0; i < 32; i += 4) { PINP4(Pz, i); PINP4(Pr, i); PINP4(Ph, i); }

        const float bh = bias[G3 + 128 + j];     // h-gate recurrent bias
        const int len = lengths[b];

        s_h8[1][7][j] = 0.0f;                    // t=0 broadcast slot (h0 = 0)
        asm volatile("s_waitcnt lgkmcnt(0)" ::: "memory");
        __builtin_amdgcn_s_barrier();            // prologue barrier

        float h = 0.0f;                          // lane j holds h_j
        const float* hprev = &s_h8[1][7][0];     // uniform row of previous h

#pragma unroll 1
        for (int k = 0; k < NCK; ++k) {
            const int pb = k & 1;
            const int tbase = k * CH;
#pragma unroll 1
            for (int tc = 0; tc < CH; ++tc) {
                // xp reads (per-lane, conflict-free) — latency hidden under bcast
                const float xz = s_xp[pb][tc][j];
                const float xr = s_xp[pb][tc][64 + j];
                const float xh = s_xp[pb][tc][128 + j];

                const float4* hp4 = (const float4*)hprev;
                v2f azp; azp.x = 0.f; azp.y = 0.f;
                v2f arp; arp.x = 0.f; arp.y = 0.f;
                v2f ahp; ahp.x = 0.f; ahp.y = 0.f;

#define PKF(ACC, WP, HV) asm("v_pk_fma_f32 %0, %1, %2, %0" \
        : "+v"(ACC) : "v"(WP), "v"(HV));

                float4 ha[8];
                // ---- half A: h[0..31] via 8 uniform b128 (HW broadcast) ----
#pragma unroll
                for (int q = 0; q < 8; ++q) ha[q] = hp4[q];
#pragma unroll
                for (int q = 0; q < 8; ++q) {
                    const v2f* hv = (const v2f*)&ha[q];
                    PKF(azp, Pz[2 * q],     hv[0])
                    PKF(arp, Pr[2 * q],     hv[0])
                    PKF(ahp, Ph[2 * q],     hv[0])
                    PKF(azp, Pz[2 * q + 1], hv[1])
                    PKF(arp, Pr[2 * q + 1], hv[1])
                    PKF(ahp, Ph[2 * q + 1], hv[1])
                }
                // ---- half B: h[32..63], reusing the same 8 float4 regs ----
#pragma unroll
                for (int q = 0; q < 8; ++q) ha[q] = hp4[8 + q];
#pragma unroll
                for (int q = 0; q < 8; ++q) {
                    const v2f* hv = (const v2f*)&ha[q];
                    PKF(azp, Pz[16 + 2 * q],     hv[0])
                    PKF(arp, Pr[16 + 2 * q],     hv[0])
                    PKF(ahp, Ph[16 + 2 * q],     hv[0])
                    PKF(azp, Pz[16 + 2 * q + 1], hv[1])
                    PKF(arp, Pr[16 + 2 * q + 1], hv[1])
                    PKF(ahp, Ph[16 + 2 * q + 1], hv[1])
                }
#undef PKF
                // horizontal adds: same grouping as R14 -> bit-identical
                const float az = azp.x + azp.y;
                const float ar = arp.x + arp.y;
                const float ah = ahp.x + ahp.y;

                const float z  = sigmoid_f(xz + az);
                const float r  = sigmoid_f(xr + ar);
                const float cc = tanh_f(xh + r * (bh + ah));
                const float hn = z * h + (1.0f - z) * cc;
                h = ((tbase + tc) < len) ? hn : h;
                s_h8[pb][tc][j] = h;             // broadcast source + head input
                // same-wave write->read ordering for next step's uniform reads
                asm volatile("s_waitcnt lgkmcnt(0)" ::: "memory");
                hprev = &s_h8[pb][tc][0];
            }
            __builtin_amdgcn_s_barrier();        // once per 8 steps
        }
    } else {
        // ================= PRODUCER (verbatim R14/R10) =================
        float Kz[FQ], Kr[FQ], Kh[FQ];
#pragma unroll
        for (int f = 0; f < FQ; ++f) {
            Kz[f] = Wk[f * G3 + j];
            Kr[f] = Wk[f * G3 + 64 + j];
            Kh[f] = Wk[f * G3 + 128 + j];
        }
        const float bz  = bias[j] + bias[G3 + j];            // fold rec bias z
        const float br  = bias[64 + j] + bias[G3 + 64 + j];  // fold rec bias r
        const float bhx = bias[128 + j];                     // input bias only
        const float dbv = db[0];
        float dwv[8];
#pragma unroll
        for (int i = 0; i < 8; ++i) dwv[i] = dw[(j & 7) * 8 + i];

        int rq[5], cq[5];
        bool act[5];
        float stg[5];
#pragma unroll
        for (int q = 0; q < 5; ++q) {
            const int idx = j + 64 * q;
            act[q] = idx < CFD;
            rq[q] = idx / FQ;
            cq[q] = idx - rq[q] * FQ;
            stg[q] = 0.0f;
        }

#define STAGE_LOAD(CK)                                                        \
        _Pragma("unroll")                                                     \
        for (int q = 0; q < 5; ++q)                                           \
            if (act[q]) stg[q] = vbp[(size_t)(CK) * CFD + j + 64 * q];
#define STAGE_WRITE(SB)                                                       \
        _Pragma("unroll")                                                     \
        for (int q = 0; q < 5; ++q)                                           \
            if (act[q]) s_v[SB][rq[q]][cq[q]] = stg[q];

#define XF(VAL, I) { az += (VAL) * Kz[I]; ar += (VAL) * Kr[I]; ah += (VAL) * Kh[I]; }
#define XPROW(BB)                                                             \
    _Pragma("unroll 1")                                                       \
    for (int row = 0; row < CH; ++row) {                                      \
        const float4* vr = (const float4*)&s_v[BB][row][0];                   \
        float az = bz, ar = br, ah = bhx;                                     \
        { float4 v0 = vr[0], v1 = vr[1], v2 = vr[2];                          \
          XF(v0.x, 0)  XF(v0.y, 1)  XF(v0.z, 2)  XF(v0.w, 3)                  \
          XF(v1.x, 4)  XF(v1.y, 5)  XF(v1.z, 6)  XF(v1.w, 7)                  \
          XF(v2.x, 8)  XF(v2.y, 9)  XF(v2.z, 10) XF(v2.w, 11) }               \
        { float4 v3 = vr[3], v4 = vr[4], v5 = vr[5];                          \
          XF(v3.x, 12) XF(v3.y, 13) XF(v3.z, 14) XF(v3.w, 15)                 \
          XF(v4.x, 16) XF(v4.y, 17) XF(v4.z, 18) XF(v4.w, 19)                 \
          XF(v5.x, 20) XF(v5.y, 21) XF(v5.z, 22) XF(v5.w, 23) }               \
        { float4 v6 = vr[6], v7 = vr[7], v8 = vr[8];                          \
          float f36 = s_v[BB][row][36];                                       \
          XF(v6.x, 24) XF(v6.y, 25) XF(v6.z, 26) XF(v6.w, 27)                 \
          XF(v7.x, 28) XF(v7.y, 29) XF(v7.z, 30) XF(v7.w, 31)                 \
          XF(v8.x, 32) XF(v8.y, 33) XF(v8.z, 34) XF(v8.w, 35)                 \
          XF(f36, 36) }                                                       \
        s_xp[BB][row][j]       = az;                                          \
        s_xp[BB][row][64 + j]  = ar;                                          \
        s_xp[BB][row][128 + j] = ah;                                          \
    }

#define HEAD(HB, TB)                                                          \
    {                                                                         \
        const int e = j & 7, s = j >> 3;                                      \
        const float4* hr = (const float4*)&s_h8[HB][s][e * 8];                \
        float4 ha = hr[0], hc = hr[1];                                        \
        float pp = ha.x * dwv[0] + ha.y * dwv[1] + ha.z * dwv[2]              \
                 + ha.w * dwv[3] + hc.x * dwv[4] + hc.y * dwv[5]              \
                 + hc.z * dwv[6] + hc.w * dwv[7];                             \
        pp += __shfl_xor(pp, 1, 64);                                          \
        pp += __shfl_xor(pp, 2, 64);                                          \
        pp += __shfl_xor(pp, 4, 64);                                          \
        if (e == 0) ob[(TB) + s] = sigmoid_f(pp + dbv);                       \
    }

        // prologue: chunk0 -> s_v[0]; chunk1 -> s_v[1]; issue chunk2; xp(chunk0)
        STAGE_LOAD(0)
        asm volatile("s_waitcnt vmcnt(0)" ::: "memory");
        STAGE_WRITE(0)
        STAGE_LOAD(1)
        asm volatile("s_waitcnt vmcnt(0)" ::: "memory");
        STAGE_WRITE(1)
        STAGE_LOAD(2)
        asm volatile("s_waitcnt lgkmcnt(0)" ::: "memory");  // own s_v visible
        XPROW(0)
        asm volatile("s_waitcnt lgkmcnt(0)" ::: "memory");
        __builtin_amdgcn_s_barrier();            // prologue barrier

#pragma unroll 1
        for (int k = 0; k < NCK; ++k) {
            const int pb = k & 1, nb = pb ^ 1;
            if (k > 0) HEAD(nb, (k - 1) * CH)
            if (k + 2 < NCK) {
                asm volatile("s_waitcnt vmcnt(0)" ::: "memory");
                STAGE_WRITE(pb)                  // chunk k+2
                if (k + 3 < NCK) STAGE_LOAD(k + 3)
            }
            if (k + 1 < NCK) XPROW(nb)           // xp chunk k+1 from s_v[nb]
            asm volatile("s_waitcnt lgkmcnt(0)" ::: "memory");
            __builtin_amdgcn_s_barrier();        // once per 8 steps
        }
        HEAD((NCK - 1) & 1, (NCK - 1) * CH)      // after final barrier: race-free

#undef STAGE_LOAD
#undef STAGE_WRITE
#undef XF
#undef XPROW
#undef HEAD
    }
}

extern "C" void kernel_launch(void* const* d_in, const int* in_sizes, int n_in,
                              void* d_out, int out_size, void* d_ws, size_t ws_size,
                              hipStream_t stream) {
    const float* values  = (const float*)d_in[2];
    const int*   lengths = (const int*)  d_in[4];
    const float* Wk      = (const float*)d_in[5];
    const float* Wr      = (const float*)d_in[6];
    const float* bias    = (const float*)d_in[7];
    const float* dw      = (const float*)d_in[8];
    const float* db      = (const float*)d_in[9];
    float* out = (float*)d_out;

    gru_ldsb<<<dim3(BQ), dim3(128), 0, stream>>>(
        values, lengths, Wk, Wr, bias, dw, db, out);
}